// Round 9
// baseline (423.563 us; speedup 1.0000x reference)
//
#include <hip/hip_runtime.h>
#include <hip/hip_fp16.h>

#define NN 50000
#define EE 800000
#define IND 256
#define HD 128

typedef _Float16 half2v __attribute__((ext_vector_type(2)));
typedef _Float16 half4v __attribute__((ext_vector_type(4)));
typedef _Float16 half8v __attribute__((ext_vector_type(8)));
typedef float f32x4 __attribute__((ext_vector_type(4)));

// ============ prep: W1T fp16 [col][k] (transposed) ============
__global__ __launch_bounds__(128) void w1t_kernel(const float* __restrict__ W1,
                                                  _Float16* __restrict__ W1T) {
  const int k = blockIdx.x;   // 0..255
  const int c = threadIdx.x;  // 0..127
  W1T[c * IND + k] = (_Float16)W1[k * HD + c];
}

// ============ prep: W2sqT fp16 [col][k] = (W2@W2)^T, b2eff = b2@W2 + b2 ============
__global__ __launch_bounds__(128) void w2sq_kernel(const float* __restrict__ W2,
                                                   const float* __restrict__ b2,
                                                   _Float16* __restrict__ W2sqT,
                                                   float* __restrict__ b2eff) {
  const int r = blockIdx.x;   // 0..127
  const int c = threadIdx.x;  // 0..127
  float acc = 0.f;
#pragma unroll 8
  for (int k = 0; k < HD; ++k)
    acc = fmaf(W2[r * HD + k], W2[k * HD + c], acc);
  W2sqT[c * HD + r] = (_Float16)acc;   // transposed store
  if (r == 0) {
    float be = b2[c];
#pragma unroll 8
    for (int k = 0; k < HD; ++k)
      be = fmaf(b2[k], W2[k * HD + c], be);
    b2eff[c] = be;
  }
}

// ============ fc1 (MFMA): h = relu(x @ W1 + b1), h fp16 ============
__global__ __launch_bounds__(256) void fc1_kernel(const float* __restrict__ x,
                                                  const _Float16* __restrict__ W1T,
                                                  const float* __restrict__ b1,
                                                  _Float16* __restrict__ h) {
  __shared__ _Float16 As[64 * 40];   // [row][k0..31] pad 40 -> 5 KB
  const int tid = threadIdx.x;
  const int l = tid & 63;
  const int w = tid >> 6;
  const int row0 = blockIdx.x * 64;
  const int lr = l & 15;       // frag row/col lane index
  const int lk = l >> 4;       // frag k-group

  f32x4 acc[4][2];
#pragma unroll
  for (int mi = 0; mi < 4; ++mi)
#pragma unroll
    for (int ni = 0; ni < 2; ++ni) acc[mi][ni] = (f32x4){0.f, 0.f, 0.f, 0.f};

#pragma unroll 1
  for (int kt = 0; kt < 8; ++kt) {
    const int k0 = kt * 32;
    __syncthreads();
#pragma unroll
    for (int i = 0; i < 2; ++i) {
      const int f = tid + i * 256;          // 0..511
      const int row = f >> 3, kq = f & 7;
      const int rg = min(row0 + row, NN - 1);
      const float4 xv = *(const float4*)&x[(size_t)rg * IND + k0 + kq * 4];
      half4v hv = {(_Float16)xv.x, (_Float16)xv.y, (_Float16)xv.z, (_Float16)xv.w};
      *(half4v*)&As[row * 40 + kq * 4] = hv;
    }
    __syncthreads();
    const half8v b0 = *(const half8v*)&W1T[(size_t)(w * 32 + lr) * IND + k0 + lk * 8];
    const half8v b1f = *(const half8v*)&W1T[(size_t)(w * 32 + 16 + lr) * IND + k0 + lk * 8];
#pragma unroll
    for (int mi = 0; mi < 4; ++mi) {
      const half8v a = *(const half8v*)&As[(mi * 16 + lr) * 40 + lk * 8];
      acc[mi][0] = __builtin_amdgcn_mfma_f32_16x16x32_f16(a, b0, acc[mi][0], 0, 0, 0);
      acc[mi][1] = __builtin_amdgcn_mfma_f32_16x16x32_f16(a, b1f, acc[mi][1], 0, 0, 0);
    }
  }
  const float bias0 = b1[w * 32 + lr];
  const float bias1 = b1[w * 32 + 16 + lr];
#pragma unroll
  for (int mi = 0; mi < 4; ++mi) {
#pragma unroll
    for (int j = 0; j < 4; ++j) {
      const int rg = row0 + mi * 16 + lk * 4 + j;
      if (rg < NN) {
        h[(size_t)rg * HD + w * 32 + lr] = (_Float16)fmaxf(acc[mi][0][j] + bias0, 0.f);
        h[(size_t)rg * HD + w * 32 + 16 + lr] = (_Float16)fmaxf(acc[mi][1][j] + bias1, 0.f);
      }
    }
  }
}

// ============ CSR build ============
__global__ void hist_kernel(const int* __restrict__ rows, int* __restrict__ counts) {
  int e = blockIdx.x * 256 + threadIdx.x;
  if (e < EE) atomicAdd(&counts[rows[e]], 1);
}

__device__ inline int wave_incl_scan(int v, int lane) {
#pragma unroll
  for (int off = 1; off < 64; off <<= 1) {
    int n = __shfl_up(v, off);
    if (lane >= off) v += n;
  }
  return v;
}

__global__ __launch_bounds__(256) void scan_a_kernel(const int* __restrict__ counts,
                                                     int* __restrict__ incl,
                                                     int* __restrict__ bsum) {
  __shared__ int wtot[4];
  const int t = threadIdx.x;
  const int i = blockIdx.x * 256 + t;
  const int lane = t & 63, wid = t >> 6;
  const int v = (i < NN) ? counts[i] : 0;
  int sc = wave_incl_scan(v, lane);
  if (lane == 63) wtot[wid] = sc;
  __syncthreads();
  int pre = 0;
#pragma unroll
  for (int w = 0; w < 3; ++w) pre += (wid > w) ? wtot[w] : 0;
  if (i < NN) incl[i] = sc + pre;
  if (t == 255) bsum[blockIdx.x] = pre + sc;
}

__global__ __launch_bounds__(256) void scan_b_kernel(int* __restrict__ bsum,
                                                     int* __restrict__ boffs,
                                                     int nblk) {
  __shared__ int wtot[4];
  const int t = threadIdx.x;
  const int lane = t & 63, wid = t >> 6;
  const int v = (t < nblk) ? bsum[t] : 0;
  int sc = wave_incl_scan(v, lane);
  if (lane == 63) wtot[wid] = sc;
  __syncthreads();
  int pre = 0;
#pragma unroll
  for (int w = 0; w < 3; ++w) pre += (wid > w) ? wtot[w] : 0;
  if (t < nblk) boffs[t] = sc + pre - v;
}

// writes row_ptr and BUCKET cursors (bucket = 64 nodes; bcur[b] = row_ptr[b*64])
__global__ __launch_bounds__(256) void scan_c_kernel(const int* __restrict__ counts,
                                                     const int* __restrict__ incl,
                                                     const int* __restrict__ boffs,
                                                     int* __restrict__ row_ptr,
                                                     int* __restrict__ bcur) {
  const int i = blockIdx.x * 256 + threadIdx.x;
  if (i == 0) row_ptr[0] = 0;
  if (i < NN) {
    const int e = boffs[blockIdx.x] + incl[i];  // inclusive prefix
    row_ptr[i + 1] = e;
    if ((i & 63) == 0) bcur[i >> 6] = e - counts[i];  // exclusive = bucket start
  }
}

// ============ pass A: scatter edges to bucket granularity ============
// 782 append cursors -> write frontier is L2-resident -> no line ping-pong.
// pack: (val_f32, row<<16 | col)  (both < 65536)
__global__ void bucket_a_kernel(const int* __restrict__ rows, const int* __restrict__ cols,
                                const float* __restrict__ vals, int* __restrict__ bcur,
                                uint2* __restrict__ edges_b) {
  int e = blockIdx.x * 256 + threadIdx.x;
  if (e < EE) {
    const int r = rows[e];
    const int pos = atomicAdd(&bcur[r >> 6], 1);
    edges_b[pos] = make_uint2(__float_as_uint(vals[e]),
                              ((unsigned)r << 16) | (unsigned)cols[e]);
  }
}

// ============ pass B: per-bucket exact CSR sort (writes stay in ~8KB range) ============
__global__ __launch_bounds__(256) void bucket_b_kernel(const uint2* __restrict__ edges_b,
                                                       const int* __restrict__ row_ptr,
                                                       uint2* __restrict__ edges_s) {
  __shared__ int cur[64];
  const int b = blockIdx.x;
  const int n0 = b * 64;
  const int nEnd = min(n0 + 64, NN);
  const int t = threadIdx.x;
  if (t < 64) cur[t] = (n0 + t < NN) ? row_ptr[n0 + t] : 0;
  __syncthreads();
  const int s = row_ptr[n0];
  const int eEnd = row_ptr[nEnd];
  for (int i = s + t; i < eEnd; i += 256) {
    const uint2 ed = edges_b[i];
    const int r = (int)(ed.y >> 16);
    const int pos = atomicAdd(&cur[r & 63], 1);
    edges_s[pos] = make_uint2(ed.x, ed.y & 0xFFFFu);
  }
}

// ============ SpMM: one wave per node, fp16 gather, fp16 agg out ============
__global__ __launch_bounds__(256) void spmm_kernel(const _Float16* __restrict__ h,
                                                   const uint2* __restrict__ edges,
                                                   const int* __restrict__ row_ptr,
                                                   _Float16* __restrict__ agg16) {
  const int wid = threadIdx.x >> 6;
  const int lane = threadIdx.x & 63;
  const int node = blockIdx.x * 4 + wid;
  if (node >= NN) return;
  const int s = row_ptr[node];
  const int e = row_ptr[node + 1];
  const unsigned* __restrict__ hu = (const unsigned*)h;
  float ax = 0.f, ay = 0.f;
  int t = s;
  for (; t + 3 < e; t += 4) {
    const uint2 e0 = edges[t + 0], e1 = edges[t + 1];
    const uint2 e2 = edges[t + 2], e3 = edges[t + 3];
    const unsigned g0 = hu[(size_t)e0.y * 64 + lane];
    const unsigned g1 = hu[(size_t)e1.y * 64 + lane];
    const unsigned g2 = hu[(size_t)e2.y * 64 + lane];
    const unsigned g3 = hu[(size_t)e3.y * 64 + lane];
    const __half2 h0 = *(const __half2*)&g0;
    const __half2 h1 = *(const __half2*)&g1;
    const __half2 h2 = *(const __half2*)&g2;
    const __half2 h3 = *(const __half2*)&g3;
    const float v0 = __uint_as_float(e0.x), v1 = __uint_as_float(e1.x);
    const float v2 = __uint_as_float(e2.x), v3 = __uint_as_float(e3.x);
    ax = fmaf(v0, __low2float(h0), ax); ay = fmaf(v0, __high2float(h0), ay);
    ax = fmaf(v1, __low2float(h1), ax); ay = fmaf(v1, __high2float(h1), ay);
    ax = fmaf(v2, __low2float(h2), ax); ay = fmaf(v2, __high2float(h2), ay);
    ax = fmaf(v3, __low2float(h3), ax); ay = fmaf(v3, __high2float(h3), ay);
  }
  for (; t < e; ++t) {
    const uint2 ee = edges[t];
    const unsigned g = hu[(size_t)ee.y * 64 + lane];
    const __half2 hh = *(const __half2*)&g;
    const float v = __uint_as_float(ee.x);
    ax = fmaf(v, __low2float(hh), ax); ay = fmaf(v, __high2float(hh), ay);
  }
  half2v o = {(_Float16)ax, (_Float16)ay};
  *(half2v*)&agg16[(size_t)node * HD + lane * 2] = o;
}

// ============ fc2+softmax (MFMA): out = softmax(agg @ W2sq + b2eff) ============
__global__ __launch_bounds__(256) void fc2sm_kernel(const _Float16* __restrict__ agg16,
                                                    const _Float16* __restrict__ W2sqT,
                                                    const float* __restrict__ b2eff,
                                                    float* __restrict__ out) {
  __shared__ _Float16 As[64 * 136];   // [row][k0..127] pad 136 -> 17.4 KB
  __shared__ float redm[64][4];
  __shared__ float reds[64][4];
  const int tid = threadIdx.x;
  const int l = tid & 63;
  const int w = tid >> 6;
  const int row0 = blockIdx.x * 64;
  const int lr = l & 15;
  const int lk = l >> 4;

  // stage A: 64 rows x 128 f16 = 1024 uint4, 4/thread
#pragma unroll
  for (int i = 0; i < 4; ++i) {
    const int f = tid + i * 256;          // 0..1023
    const int row = f >> 4, q = f & 15;
    const int rg = min(row0 + row, NN - 1);
    *(uint4*)&As[row * 136 + q * 8] = *(const uint4*)&agg16[(size_t)rg * HD + q * 8];
  }
  __syncthreads();

  f32x4 acc[4][2];
#pragma unroll
  for (int mi = 0; mi < 4; ++mi)
#pragma unroll
    for (int ni = 0; ni < 2; ++ni) acc[mi][ni] = (f32x4){0.f, 0.f, 0.f, 0.f};

#pragma unroll 2
  for (int kt = 0; kt < 4; ++kt) {
    const int k0 = kt * 32;
    const half8v b0 = *(const half8v*)&W2sqT[(size_t)(w * 32 + lr) * HD + k0 + lk * 8];
    const half8v b1f = *(const half8v*)&W2sqT[(size_t)(w * 32 + 16 + lr) * HD + k0 + lk * 8];
#pragma unroll
    for (int mi = 0; mi < 4; ++mi) {
      const half8v a = *(const half8v*)&As[(mi * 16 + lr) * 136 + k0 + lk * 8];
      acc[mi][0] = __builtin_amdgcn_mfma_f32_16x16x32_f16(a, b0, acc[mi][0], 0, 0, 0);
      acc[mi][1] = __builtin_amdgcn_mfma_f32_16x16x32_f16(a, b1f, acc[mi][1], 0, 0, 0);
    }
  }

  const float be0 = b2eff[w * 32 + lr];
  const float be1 = b2eff[w * 32 + 16 + lr];
#pragma unroll
  for (int mi = 0; mi < 4; ++mi)
#pragma unroll
    for (int j = 0; j < 4; ++j) {
      acc[mi][0][j] += be0;
      acc[mi][1][j] += be1;
    }
#pragma unroll
  for (int mi = 0; mi < 4; ++mi)
#pragma unroll
    for (int j = 0; j < 4; ++j) {
      float v = fmaxf(acc[mi][0][j], acc[mi][1][j]);
      v = fmaxf(v, __shfl_xor(v, 1));
      v = fmaxf(v, __shfl_xor(v, 2));
      v = fmaxf(v, __shfl_xor(v, 4));
      v = fmaxf(v, __shfl_xor(v, 8));
      if (lr == 0) redm[mi * 16 + lk * 4 + j][w] = v;
    }
  __syncthreads();
#pragma unroll
  for (int mi = 0; mi < 4; ++mi)
#pragma unroll
    for (int j = 0; j < 4; ++j) {
      const int row = mi * 16 + lk * 4 + j;
      const float m = fmaxf(fmaxf(redm[row][0], redm[row][1]),
                            fmaxf(redm[row][2], redm[row][3]));
      const float e0 = __expf(acc[mi][0][j] - m);
      const float e1 = __expf(acc[mi][1][j] - m);
      acc[mi][0][j] = e0;
      acc[mi][1][j] = e1;
      float s = e0 + e1;
      s += __shfl_xor(s, 1);
      s += __shfl_xor(s, 2);
      s += __shfl_xor(s, 4);
      s += __shfl_xor(s, 8);
      if (lr == 0) reds[row][w] = s;
    }
  __syncthreads();
#pragma unroll
  for (int mi = 0; mi < 4; ++mi)
#pragma unroll
    for (int j = 0; j < 4; ++j) {
      const int row = mi * 16 + lk * 4 + j;
      const int rg = row0 + row;
      if (rg < NN) {
        const float inv = 1.f / (((reds[row][0] + reds[row][1]) +
                                  (reds[row][2] + reds[row][3])));
        out[(size_t)rg * HD + w * 32 + lr] = acc[mi][0][j] * inv;
        out[(size_t)rg * HD + w * 32 + 16 + lr] = acc[mi][1][j] * inv;
      }
    }
}

// ============ launch ============
extern "C" void kernel_launch(void* const* d_in, const int* in_sizes, int n_in,
                              void* d_out, int out_size, void* d_ws, size_t ws_size,
                              hipStream_t stream) {
  (void)in_sizes; (void)n_in; (void)out_size; (void)ws_size;
  const float* x   = (const float*)d_in[0];
  const float* W1  = (const float*)d_in[1];
  const float* b1  = (const float*)d_in[2];
  const float* W2  = (const float*)d_in[3];
  const float* b2  = (const float*)d_in[4];
  const float* adj_vals = (const float*)d_in[5];
  const int* adj_rows   = (const int*)d_in[6];
  const int* adj_cols   = (const int*)d_in[7];
  float* out = (float*)d_out;

  char* ws = (char*)d_ws;
  _Float16* h      = (_Float16*)ws;                       // 12.8 MB
  _Float16* agg16  = (_Float16*)(ws + 12800000);          // 12.8 MB
  _Float16* W1T    = (_Float16*)(ws + 25600000);          // 64 KB
  _Float16* W2sqT  = (_Float16*)(ws + 25665536);          // 32 KB
  float* b2eff     = (float*)(ws + 25698304);             // 512 B
  int* row_ptr     = (int*)(ws + 25698816);               // 50016 ints
  int* bcur        = (int*)(ws + 25898880);               // 800 ints
  int* counts      = (int*)(ws + 26098944);
  int* incl        = (int*)(ws + 26299008);
  int* bsum        = (int*)(ws + 26499072);               // 256 ints
  int* boffs       = (int*)(ws + 26500096);               // 256 ints
  uint2* edges_b   = (uint2*)(ws + 26501120);             // 6.4 MB
  uint2* edges_s   = (uint2*)(ws + 32901120);             // 6.4 MB

  const int nblk = (NN + 255) / 256;   // 196
  const int nbkt = (NN + 63) / 64;     // 782

  hipMemsetAsync(counts, 0, NN * sizeof(int), stream);

  w1t_kernel<<<IND, HD, 0, stream>>>(W1, W1T);
  w2sq_kernel<<<HD, HD, 0, stream>>>(W2, b2, W2sqT, b2eff);
  fc1_kernel<<<(NN + 63) / 64, 256, 0, stream>>>(x, W1T, b1, h);
  hist_kernel<<<(EE + 255) / 256, 256, 0, stream>>>(adj_rows, counts);
  scan_a_kernel<<<nblk, 256, 0, stream>>>(counts, incl, bsum);
  scan_b_kernel<<<1, 256, 0, stream>>>(bsum, boffs, nblk);
  scan_c_kernel<<<nblk, 256, 0, stream>>>(counts, incl, boffs, row_ptr, bcur);
  bucket_a_kernel<<<(EE + 255) / 256, 256, 0, stream>>>(adj_rows, adj_cols, adj_vals,
                                                        bcur, edges_b);
  bucket_b_kernel<<<nbkt, 256, 0, stream>>>(edges_b, row_ptr, edges_s);
  spmm_kernel<<<(NN + 3) / 4, 256, 0, stream>>>(h, edges_s, row_ptr, agg16);
  fc2sm_kernel<<<(NN + 63) / 64, 256, 0, stream>>>(agg16, W2sqT, b2eff, out);
}

// Round 10
// 254.526 us; speedup vs baseline: 1.6641x; 1.6641x over previous
//
#include <hip/hip_runtime.h>
#include <hip/hip_fp16.h>

#define NN 50000
#define EE 800000
#define IND 256
#define HD 128
#define EPB 4096                       // edges per scatter block
#define GBLK 196                       // ceil(EE / EPB)
#define NBIN 196                       // ceil(NN / 256), bin = row >> 8

typedef _Float16 half2v __attribute__((ext_vector_type(2)));
typedef _Float16 half4v __attribute__((ext_vector_type(4)));
typedef _Float16 half8v __attribute__((ext_vector_type(8)));
typedef float f32x4 __attribute__((ext_vector_type(4)));

// ============ prep: W1T fp16 [col][k] ============
__global__ __launch_bounds__(128) void w1t_kernel(const float* __restrict__ W1,
                                                  _Float16* __restrict__ W1T) {
  const int k = blockIdx.x;
  const int c = threadIdx.x;
  W1T[c * IND + k] = (_Float16)W1[k * HD + c];
}

// ============ prep: W2sqT fp16 [col][k] = (W2@W2)^T, b2eff = b2@W2 + b2 ============
__global__ __launch_bounds__(128) void w2sq_kernel(const float* __restrict__ W2,
                                                   const float* __restrict__ b2,
                                                   _Float16* __restrict__ W2sqT,
                                                   float* __restrict__ b2eff) {
  const int r = blockIdx.x;
  const int c = threadIdx.x;
  float acc = 0.f;
#pragma unroll 8
  for (int k = 0; k < HD; ++k)
    acc = fmaf(W2[r * HD + k], W2[k * HD + c], acc);
  W2sqT[c * HD + r] = (_Float16)acc;
  if (r == 0) {
    float be = b2[c];
#pragma unroll 8
    for (int k = 0; k < HD; ++k)
      be = fmaf(b2[k], W2[k * HD + c], be);
    b2eff[c] = be;
  }
}

// ============ fc1 (MFMA): h = relu(x @ W1 + b1), h fp16 ============
__global__ __launch_bounds__(256) void fc1_kernel(const float* __restrict__ x,
                                                  const _Float16* __restrict__ W1T,
                                                  const float* __restrict__ b1,
                                                  _Float16* __restrict__ h) {
  __shared__ _Float16 As[64 * 40];
  const int tid = threadIdx.x;
  const int l = tid & 63;
  const int w = tid >> 6;
  const int row0 = blockIdx.x * 64;
  const int lr = l & 15;
  const int lk = l >> 4;

  f32x4 acc[4][2];
#pragma unroll
  for (int mi = 0; mi < 4; ++mi)
#pragma unroll
    for (int ni = 0; ni < 2; ++ni) acc[mi][ni] = (f32x4){0.f, 0.f, 0.f, 0.f};

#pragma unroll 1
  for (int kt = 0; kt < 8; ++kt) {
    const int k0 = kt * 32;
    __syncthreads();
#pragma unroll
    for (int i = 0; i < 2; ++i) {
      const int f = tid + i * 256;
      const int row = f >> 3, kq = f & 7;
      const int rg = min(row0 + row, NN - 1);
      const float4 xv = *(const float4*)&x[(size_t)rg * IND + k0 + kq * 4];
      half4v hv = {(_Float16)xv.x, (_Float16)xv.y, (_Float16)xv.z, (_Float16)xv.w};
      *(half4v*)&As[row * 40 + kq * 4] = hv;
    }
    __syncthreads();
    const half8v b0 = *(const half8v*)&W1T[(size_t)(w * 32 + lr) * IND + k0 + lk * 8];
    const half8v b1f = *(const half8v*)&W1T[(size_t)(w * 32 + 16 + lr) * IND + k0 + lk * 8];
#pragma unroll
    for (int mi = 0; mi < 4; ++mi) {
      const half8v a = *(const half8v*)&As[(mi * 16 + lr) * 40 + lk * 8];
      acc[mi][0] = __builtin_amdgcn_mfma_f32_16x16x32_f16(a, b0, acc[mi][0], 0, 0, 0);
      acc[mi][1] = __builtin_amdgcn_mfma_f32_16x16x32_f16(a, b1f, acc[mi][1], 0, 0, 0);
    }
  }
  const float bias0 = b1[w * 32 + lr];
  const float bias1 = b1[w * 32 + 16 + lr];
#pragma unroll
  for (int mi = 0; mi < 4; ++mi) {
#pragma unroll
    for (int j = 0; j < 4; ++j) {
      const int rg = row0 + mi * 16 + lk * 4 + j;
      if (rg < NN) {
        h[(size_t)rg * HD + w * 32 + lr] = (_Float16)fmaxf(acc[mi][0][j] + bias0, 0.f);
        h[(size_t)rg * HD + w * 32 + 16 + lr] = (_Float16)fmaxf(acc[mi][1][j] + bias1, 0.f);
      }
    }
  }
}

// ============ node-degree histogram ============
__global__ void hist_kernel(const int* __restrict__ rows, int* __restrict__ counts) {
  int e = blockIdx.x * 256 + threadIdx.x;
  if (e < EE) atomicAdd(&counts[rows[e]], 1);
}

__device__ inline int wave_incl_scan(int v, int lane) {
#pragma unroll
  for (int off = 1; off < 64; off <<= 1) {
    int n = __shfl_up(v, off);
    if (lane >= off) v += n;
  }
  return v;
}

__global__ __launch_bounds__(256) void scan_a_kernel(const int* __restrict__ counts,
                                                     int* __restrict__ incl,
                                                     int* __restrict__ bsum) {
  __shared__ int wtot[4];
  const int t = threadIdx.x;
  const int i = blockIdx.x * 256 + t;
  const int lane = t & 63, wid = t >> 6;
  const int v = (i < NN) ? counts[i] : 0;
  int sc = wave_incl_scan(v, lane);
  if (lane == 63) wtot[wid] = sc;
  __syncthreads();
  int pre = 0;
#pragma unroll
  for (int w = 0; w < 3; ++w) pre += (wid > w) ? wtot[w] : 0;
  if (i < NN) incl[i] = sc + pre;
  if (t == 255) bsum[blockIdx.x] = pre + sc;
}

__global__ __launch_bounds__(256) void scan_b_kernel(int* __restrict__ bsum,
                                                     int* __restrict__ boffs,
                                                     int nblk) {
  __shared__ int wtot[4];
  const int t = threadIdx.x;
  const int lane = t & 63, wid = t >> 6;
  const int v = (t < nblk) ? bsum[t] : 0;
  int sc = wave_incl_scan(v, lane);
  if (lane == 63) wtot[wid] = sc;
  __syncthreads();
  int pre = 0;
#pragma unroll
  for (int w = 0; w < 3; ++w) pre += (wid > w) ? wtot[w] : 0;
  if (t < nblk) boffs[t] = sc + pre - v;
}

__global__ __launch_bounds__(256) void scan_c_kernel(const int* __restrict__ incl,
                                                     const int* __restrict__ boffs,
                                                     int* __restrict__ row_ptr) {
  const int i = blockIdx.x * 256 + threadIdx.x;
  if (i == 0) row_ptr[0] = 0;
  if (i < NN) row_ptr[i + 1] = boffs[blockIdx.x] + incl[i];
}

// ============ radix pass 1: per-(block,bin) counts, LDS atomics only ============
__global__ __launch_bounds__(256) void count_kernel(const int* __restrict__ rows,
                                                    int* __restrict__ countmat) {
  __shared__ int cnt[NBIN];
  const int t = threadIdx.x, blk = blockIdx.x;
  for (int i = t; i < NBIN; i += 256) cnt[i] = 0;
  __syncthreads();
  const int e0 = blk * EPB;
  const int eN = min(e0 + EPB, EE);
  for (int e = e0 + t; e < eN; e += 256) atomicAdd(&cnt[rows[e] >> 8], 1);
  __syncthreads();
  for (int i = t; i < NBIN; i += 256) countmat[i * GBLK + blk] = cnt[i];  // [bin][blk]
}

// ============ radix pass 2: per-bin scan over blocks -> exact offsets ============
__global__ __launch_bounds__(256) void scanmat_kernel(const int* __restrict__ countmat,
                                                      const int* __restrict__ row_ptr,
                                                      int* __restrict__ offmat) {
  __shared__ int wtot[4];
  const int bin = blockIdx.x;
  const int t = threadIdx.x, lane = t & 63, wid = t >> 6;
  const int v = (t < GBLK) ? countmat[bin * GBLK + t] : 0;
  int sc = wave_incl_scan(v, lane);
  if (lane == 63) wtot[wid] = sc;
  __syncthreads();
  int pre = 0;
#pragma unroll
  for (int w = 0; w < 3; ++w) pre += (wid > w) ? wtot[w] : 0;
  const int binbase = row_ptr[bin << 8];
  if (t < GBLK) offmat[bin * GBLK + t] = binbase + pre + sc - v;
}

// ============ radix pass 3: LDS-bin + coalesced run writes to exact slots ============
__global__ __launch_bounds__(256) void scatter_kernel(const int* __restrict__ rows,
                                                      const int* __restrict__ cols,
                                                      const float* __restrict__ vals,
                                                      const int* __restrict__ offmat,
                                                      uint2* __restrict__ edges_b) {
  __shared__ uint2 st[EPB];                 // 32 KB
  __shared__ unsigned char binof[EPB];      // 4 KB
  __shared__ int cnt[NBIN], lofs[NBIN], gbase[NBIN];
  __shared__ int wtot[4];
  const int t = threadIdx.x, blk = blockIdx.x;
  const int lane = t & 63, wid = t >> 6;
  for (int i = t; i < NBIN; i += 256) cnt[i] = 0;
  __syncthreads();
  const int e0 = blk * EPB;
  const int n = min(EPB, EE - e0);
  for (int i = t; i < n; i += 256) atomicAdd(&cnt[rows[e0 + i] >> 8], 1);
  __syncthreads();
  {
    const int v = (t < NBIN) ? cnt[t] : 0;
    int sc = wave_incl_scan(v, lane);
    if (lane == 63) wtot[wid] = sc;
    __syncthreads();
    int pre = 0;
#pragma unroll
    for (int w = 0; w < 3; ++w) pre += (wid > w) ? wtot[w] : 0;
    if (t < NBIN) {
      lofs[t] = pre + sc - v;
      gbase[t] = offmat[t * GBLK + blk];
    }
  }
  __syncthreads();
  for (int i = t; i < NBIN; i += 256) cnt[i] = 0;
  __syncthreads();
  for (int i = t; i < n; i += 256) {
    const int r = rows[e0 + i];
    const int b = r >> 8;
    const int p = atomicAdd(&cnt[b], 1);    // LDS atomic, ~21/bin
    const int j = lofs[b] + p;
    st[j] = make_uint2(__float_as_uint(vals[e0 + i]),
                       ((unsigned)r << 16) | (unsigned)cols[e0 + i]);
    binof[j] = (unsigned char)b;
  }
  __syncthreads();
  for (int j = t; j < n; j += 256) {        // consecutive j -> same bin run -> coalesced
    const int b = binof[j];
    edges_b[gbase[b] + (j - lofs[b])] = st[j];
  }
}

// ============ radix pass 4: exact CSR within a 256-node bin (L2-windowed) ============
__global__ __launch_bounds__(256) void binsort_kernel(const uint2* __restrict__ edges_b,
                                                      const int* __restrict__ row_ptr,
                                                      uint2* __restrict__ edges_s) {
  __shared__ int cur[256];
  const int bin = blockIdx.x;
  const int n0 = bin << 8;
  const int nEnd = min(n0 + 256, NN);
  const int t = threadIdx.x;
  if (n0 + t < nEnd) cur[t] = row_ptr[n0 + t];
  __syncthreads();
  const int s = row_ptr[n0];
  const int eEnd = row_ptr[nEnd];
  for (int i = s + t; i < eEnd; i += 256) {
    const uint2 ed = edges_b[i];
    const int r = (int)(ed.y >> 16);
    const int pos = atomicAdd(&cur[r & 255], 1);   // LDS atomic, ~16/node
    edges_s[pos] = make_uint2(ed.x, ed.y & 0xFFFFu);
  }
}

// ============ SpMM: one wave per node, fp16 gather, fp16 agg out ============
__global__ __launch_bounds__(256) void spmm_kernel(const _Float16* __restrict__ h,
                                                   const uint2* __restrict__ edges,
                                                   const int* __restrict__ row_ptr,
                                                   _Float16* __restrict__ agg16) {
  const int wid = threadIdx.x >> 6;
  const int lane = threadIdx.x & 63;
  const int node = blockIdx.x * 4 + wid;
  if (node >= NN) return;
  const int s = row_ptr[node];
  const int e = row_ptr[node + 1];
  const unsigned* __restrict__ hu = (const unsigned*)h;
  float ax = 0.f, ay = 0.f;
  int t = s;
  for (; t + 3 < e; t += 4) {
    const uint2 e0 = edges[t + 0], e1 = edges[t + 1];
    const uint2 e2 = edges[t + 2], e3 = edges[t + 3];
    const unsigned g0 = hu[(size_t)e0.y * 64 + lane];
    const unsigned g1 = hu[(size_t)e1.y * 64 + lane];
    const unsigned g2 = hu[(size_t)e2.y * 64 + lane];
    const unsigned g3 = hu[(size_t)e3.y * 64 + lane];
    const __half2 h0 = *(const __half2*)&g0;
    const __half2 h1 = *(const __half2*)&g1;
    const __half2 h2 = *(const __half2*)&g2;
    const __half2 h3 = *(const __half2*)&g3;
    const float v0 = __uint_as_float(e0.x), v1 = __uint_as_float(e1.x);
    const float v2 = __uint_as_float(e2.x), v3 = __uint_as_float(e3.x);
    ax = fmaf(v0, __low2float(h0), ax); ay = fmaf(v0, __high2float(h0), ay);
    ax = fmaf(v1, __low2float(h1), ax); ay = fmaf(v1, __high2float(h1), ay);
    ax = fmaf(v2, __low2float(h2), ax); ay = fmaf(v2, __high2float(h2), ay);
    ax = fmaf(v3, __low2float(h3), ax); ay = fmaf(v3, __high2float(h3), ay);
  }
  for (; t < e; ++t) {
    const uint2 ee = edges[t];
    const unsigned g = hu[(size_t)ee.y * 64 + lane];
    const __half2 hh = *(const __half2*)&g;
    const float v = __uint_as_float(ee.x);
    ax = fmaf(v, __low2float(hh), ax); ay = fmaf(v, __high2float(hh), ay);
  }
  half2v o = {(_Float16)ax, (_Float16)ay};
  *(half2v*)&agg16[(size_t)node * HD + lane * 2] = o;
}

// ============ fc2+softmax (MFMA): out = softmax(agg @ W2sq + b2eff) ============
__global__ __launch_bounds__(256) void fc2sm_kernel(const _Float16* __restrict__ agg16,
                                                    const _Float16* __restrict__ W2sqT,
                                                    const float* __restrict__ b2eff,
                                                    float* __restrict__ out) {
  __shared__ _Float16 As[64 * 136];
  __shared__ float redm[64][4];
  __shared__ float reds[64][4];
  const int tid = threadIdx.x;
  const int l = tid & 63;
  const int w = tid >> 6;
  const int row0 = blockIdx.x * 64;
  const int lr = l & 15;
  const int lk = l >> 4;

#pragma unroll
  for (int i = 0; i < 4; ++i) {
    const int f = tid + i * 256;
    const int row = f >> 4, q = f & 15;
    const int rg = min(row0 + row, NN - 1);
    *(uint4*)&As[row * 136 + q * 8] = *(const uint4*)&agg16[(size_t)rg * HD + q * 8];
  }
  __syncthreads();

  f32x4 acc[4][2];
#pragma unroll
  for (int mi = 0; mi < 4; ++mi)
#pragma unroll
    for (int ni = 0; ni < 2; ++ni) acc[mi][ni] = (f32x4){0.f, 0.f, 0.f, 0.f};

#pragma unroll 2
  for (int kt = 0; kt < 4; ++kt) {
    const int k0 = kt * 32;
    const half8v b0 = *(const half8v*)&W2sqT[(size_t)(w * 32 + lr) * HD + k0 + lk * 8];
    const half8v b1f = *(const half8v*)&W2sqT[(size_t)(w * 32 + 16 + lr) * HD + k0 + lk * 8];
#pragma unroll
    for (int mi = 0; mi < 4; ++mi) {
      const half8v a = *(const half8v*)&As[(mi * 16 + lr) * 136 + k0 + lk * 8];
      acc[mi][0] = __builtin_amdgcn_mfma_f32_16x16x32_f16(a, b0, acc[mi][0], 0, 0, 0);
      acc[mi][1] = __builtin_amdgcn_mfma_f32_16x16x32_f16(a, b1f, acc[mi][1], 0, 0, 0);
    }
  }

  const float be0 = b2eff[w * 32 + lr];
  const float be1 = b2eff[w * 32 + 16 + lr];
#pragma unroll
  for (int mi = 0; mi < 4; ++mi)
#pragma unroll
    for (int j = 0; j < 4; ++j) {
      acc[mi][0][j] += be0;
      acc[mi][1][j] += be1;
    }
#pragma unroll
  for (int mi = 0; mi < 4; ++mi)
#pragma unroll
    for (int j = 0; j < 4; ++j) {
      float v = fmaxf(acc[mi][0][j], acc[mi][1][j]);
      v = fmaxf(v, __shfl_xor(v, 1));
      v = fmaxf(v, __shfl_xor(v, 2));
      v = fmaxf(v, __shfl_xor(v, 4));
      v = fmaxf(v, __shfl_xor(v, 8));
      if (lr == 0) redm[mi * 16 + lk * 4 + j][w] = v;
    }
  __syncthreads();
#pragma unroll
  for (int mi = 0; mi < 4; ++mi)
#pragma unroll
    for (int j = 0; j < 4; ++j) {
      const int row = mi * 16 + lk * 4 + j;
      const float m = fmaxf(fmaxf(redm[row][0], redm[row][1]),
                            fmaxf(redm[row][2], redm[row][3]));
      const float e0 = __expf(acc[mi][0][j] - m);
      const float e1 = __expf(acc[mi][1][j] - m);
      acc[mi][0][j] = e0;
      acc[mi][1][j] = e1;
      float s = e0 + e1;
      s += __shfl_xor(s, 1);
      s += __shfl_xor(s, 2);
      s += __shfl_xor(s, 4);
      s += __shfl_xor(s, 8);
      if (lr == 0) reds[row][w] = s;
    }
  __syncthreads();
#pragma unroll
  for (int mi = 0; mi < 4; ++mi)
#pragma unroll
    for (int j = 0; j < 4; ++j) {
      const int row = mi * 16 + lk * 4 + j;
      const int rg = row0 + row;
      if (rg < NN) {
        const float inv = 1.f / (((reds[row][0] + reds[row][1]) +
                                  (reds[row][2] + reds[row][3])));
        out[(size_t)rg * HD + w * 32 + lr] = acc[mi][0][j] * inv;
        out[(size_t)rg * HD + w * 32 + 16 + lr] = acc[mi][1][j] * inv;
      }
    }
}

// ============ launch ============
extern "C" void kernel_launch(void* const* d_in, const int* in_sizes, int n_in,
                              void* d_out, int out_size, void* d_ws, size_t ws_size,
                              hipStream_t stream) {
  (void)in_sizes; (void)n_in; (void)out_size; (void)ws_size;
  const float* x   = (const float*)d_in[0];
  const float* W1  = (const float*)d_in[1];
  const float* b1  = (const float*)d_in[2];
  const float* W2  = (const float*)d_in[3];
  const float* b2  = (const float*)d_in[4];
  const float* adj_vals = (const float*)d_in[5];
  const int* adj_rows   = (const int*)d_in[6];
  const int* adj_cols   = (const int*)d_in[7];
  float* out = (float*)d_out;

  char* ws = (char*)d_ws;
  _Float16* h      = (_Float16*)ws;                       // 12.8 MB
  _Float16* agg16  = (_Float16*)(ws + 12800000);          // 12.8 MB
  _Float16* W1T    = (_Float16*)(ws + 25600000);          // 64 KB
  _Float16* W2sqT  = (_Float16*)(ws + 25665536);          // 32 KB
  float* b2eff     = (float*)(ws + 25698304);             // 512 B
  int* row_ptr     = (int*)(ws + 25698816);               // 200,064 B
  int* counts      = (int*)(ws + 25898880);               // 200,064 B
  int* incl        = (int*)(ws + 26098944);               // 200,064 B
  int* bsum        = (int*)(ws + 26299008);               // 1 KB
  int* boffs       = (int*)(ws + 26300032);               // 1 KB
  int* countmat    = (int*)(ws + 26301056);               // 153,664 B
  int* offmat      = (int*)(ws + 26454720);               // 153,664 B
  uint2* edges_b   = (uint2*)(ws + 26608384);             // 6.4 MB
  uint2* edges_s   = (uint2*)(ws + 33008384);             // 6.4 MB

  const int nblk = (NN + 255) / 256;   // 196

  hipMemsetAsync(counts, 0, NN * sizeof(int), stream);

  w1t_kernel<<<IND, HD, 0, stream>>>(W1, W1T);
  w2sq_kernel<<<HD, HD, 0, stream>>>(W2, b2, W2sqT, b2eff);
  fc1_kernel<<<(NN + 63) / 64, 256, 0, stream>>>(x, W1T, b1, h);
  hist_kernel<<<(EE + 255) / 256, 256, 0, stream>>>(adj_rows, counts);
  scan_a_kernel<<<nblk, 256, 0, stream>>>(counts, incl, bsum);
  scan_b_kernel<<<1, 256, 0, stream>>>(bsum, boffs, nblk);
  scan_c_kernel<<<nblk, 256, 0, stream>>>(incl, boffs, row_ptr);
  count_kernel<<<GBLK, 256, 0, stream>>>(adj_rows, countmat);
  scanmat_kernel<<<NBIN, 256, 0, stream>>>(countmat, row_ptr, offmat);
  scatter_kernel<<<GBLK, 256, 0, stream>>>(adj_rows, adj_cols, adj_vals, offmat, edges_b);
  binsort_kernel<<<NBIN, 256, 0, stream>>>(edges_b, row_ptr, edges_s);
  spmm_kernel<<<(NN + 3) / 4, 256, 0, stream>>>(h, edges_s, row_ptr, agg16);
  fc2sm_kernel<<<(NN + 63) / 64, 256, 0, stream>>>(agg16, W2sqT, b2eff, out);
}